// Round 14
// baseline (554.624 us; speedup 1.0000x reference)
//
#include <hip/hip_runtime.h>
#include <hip/hip_cooperative_groups.h>
#include <cstdint>
#include <cstddef>

#define HIDDIM 128
#define NGRAPH_MAX 512
#define LDSPAD 136   // 128 + 8 bf16 pad: row stride 272B (16B-aligned, bank-conflict-free frag reads)
#define NBKT_MAX 512 // coarse buckets of 256 nodes (dst>>8); N<=131072

// r14: aggc is at compulsory traffic (r13: 179.5MB = 8 XCDs x ~86% of x fetched
// once) and fabric-rate-limited at 3.6 TB/s -- left untouched. This round:
// (1) bscatter flush fixed (r13 regression: serial per-bucket copy -> parallel
// per-element via sbkt[] bucket-id array); (2) the whole CSR chain (scans +
// depth col | scatter | build) fused into ONE cooperative kernel with grid.sync,
// removing 2 launch boundaries and serializations.

using short8 = __attribute__((ext_vector_type(8))) short;
using f32x4  = __attribute__((ext_vector_type(4))) float;

__device__ __forceinline__ unsigned short f2bf(float x) {
    union { float f; uint32_t u; } v; v.f = x;
    uint32_t r = v.u + 0x7fffu + ((v.u >> 16) & 1u);   // RNE
    return (unsigned short)(r >> 16);
}
__device__ __forceinline__ uint32_t pack2(float a, float b) {
    return (uint32_t)f2bf(a) | ((uint32_t)f2bf(b) << 16);
}
__device__ __forceinline__ float bflo(uint32_t u) { return __uint_as_float(u << 16); }
__device__ __forceinline__ float bfhi(uint32_t u) { return __uint_as_float(u & 0xffff0000u); }

// ---------------------------------------------------------------- fused prep: feat | bcount | nodestats | wt
__global__ void k_prep(const int* __restrict__ nt, const int* __restrict__ ih,
                       const float* __restrict__ flags, const int* __restrict__ depth,
                       const float* __restrict__ embN, const float* __restrict__ embI,
                       const int* __restrict__ edst, const int* __restrict__ batch,
                       const float* __restrict__ Wn0, const float* __restrict__ Ws0,
                       const float* __restrict__ Wn1, const float* __restrict__ Ws1,
                       int K0, int N, int E, int G,
                       unsigned short* __restrict__ x0, unsigned short* __restrict__ Wt,
                       int* __restrict__ bcount, int* __restrict__ counts,
                       int* __restrict__ maxd,
                       int nbF, int nbC, int nbN) {
    __shared__ int hist[NBKT_MAX];
    __shared__ int red[256];
    int b = blockIdx.x, t = threadIdx.x;
    if (b < nbF) {
        // ---- node features: 16 threads/node, one uint4 (8 bf16 cols) each
        int idx = b * 256 + t;
        int i = idx >> 4;
        int seg = idx & 15;
        if (i >= N) return;
        uint4 o = make_uint4(0u, 0u, 0u, 0u);
        if (seg < 8) {
            const float4* r = (const float4*)(embN + (size_t)nt[i] * 64 + seg * 8);
            float4 v0 = r[0], v1 = r[1];
            o.x = pack2(v0.x, v0.y); o.y = pack2(v0.z, v0.w);
            o.z = pack2(v1.x, v1.y); o.w = pack2(v1.z, v1.w);
        } else if (seg < 12) {
            const float4* r = (const float4*)(embI + (size_t)ih[i] * 32 + (seg - 8) * 8);
            float4 v0 = r[0], v1 = r[1];
            o.x = pack2(v0.x, v0.y); o.y = pack2(v0.z, v0.w);
            o.z = pack2(v1.x, v1.y); o.w = pack2(v1.z, v1.w);
        } else if (seg == 12) {
            const float* fp = flags + (size_t)i * 5;
            o.x = pack2(fp[0], fp[1]);
            o.y = pack2(fp[2], fp[3]);
            o.z = pack2(fp[4], 0.f);   // col101 (depth) written in k_csr phase 0
        } // seg 13..15: zeros
        *(uint4*)(x0 + (size_t)i * HIDDIM + seg * 8) = o;
    } else if (b < nbF + nbC) {
        hist[t] = 0; hist[t + 256] = 0;
        __syncthreads();
        int c0 = (b - nbF) * 4096;
        int ce = min(4096, E - c0);
        for (int i = t; i < ce; i += 256)
            atomicAdd(&hist[edst[c0 + i] >> 8], 1);
        __syncthreads();
        for (int bb = t; bb < NBKT_MAX; bb += 256)
            if (hist[bb]) atomicAdd(&bcount[bb], hist[bb]);
    } else if (b < nbF + nbC + nbN) {
        for (int g = t; g < G; g += 256) hist[g] = 0;
        __syncthreads();
        int i = (b - nbF - nbC) * 256 + t;
        int d = 0;
        if (i < N) {
            atomicAdd(&hist[batch[i]], 1);
            d = depth[i];
        }
        red[t] = d;
        __syncthreads();
        for (int off = 128; off > 0; off >>= 1) {
            if (t < off) red[t] = max(red[t], red[t + off]);
            __syncthreads();
        }
        if (t == 0) atomicMax(maxd, red[0]);
        for (int g = t; g < G; g += 256)
            if (hist[g]) atomicAdd(&counts[g], hist[g]);
    } else {
        int idx = (b - nbF - nbC - nbN) * 256 + t;   // 65536 total
        int mat = idx >> 14;
        int rem = idx & 16383;
        int n = rem >> 7, k = rem & 127;
        const float* W = (mat == 0) ? Wn0 : (mat == 1) ? Ws0 : (mat == 2) ? Wn1 : Ws1;
        int K = (mat < 2) ? K0 : HIDDIM;
        Wt[(size_t)mat * HIDDIM * HIDDIM + n * HIDDIM + k] =
            (k < K) ? f2bf(W[(size_t)k * HIDDIM + n]) : (unsigned short)0;
    }
}

// ---------------------------------------------------------------- cooperative CSR build:
// phase0: boff/bcur scan (blk 0) | gstart scan (blk 1) | depth col (blks 2+)
// phase1: bucket scatter (LDS sort, parallel sbkt flush)
// phase2: per-bucket deg/rowptr/invd/srcs
__global__ void k_csr(const int* __restrict__ src, const int* __restrict__ dst,
                      const int* __restrict__ bcount, int* __restrict__ boff,
                      int* __restrict__ bcur, int* __restrict__ rowptr,
                      const int* __restrict__ counts, int* __restrict__ gstart,
                      const int* __restrict__ depth, const int* __restrict__ maxd,
                      unsigned short* __restrict__ x0,
                      uint32_t* __restrict__ ebuf, float* __restrict__ invd,
                      int* __restrict__ srcs,
                      int nbkt, int N, int E, int G, int nbC) {
    cooperative_groups::grid_group grid = cooperative_groups::this_grid();
    __shared__ uint32_t stage[4096];        // 16 KB
    __shared__ unsigned short sbkt[4096];   // 8 KB (bucket id per staged slot)
    __shared__ int hist[NBKT_MAX];          // 2 KB (reused as ldeg in phase 2)
    __shared__ int ofs[NBKT_MAX];           // 2 KB (reused as lofs)
    __shared__ int cur[NBKT_MAX];           // 2 KB (reused as lcur)
    __shared__ int gbase[NBKT_MAX];         // 2 KB
    __shared__ int scanbuf[256];            // 1 KB
    int b = blockIdx.x, t = threadIdx.x;

    // ---- phase 0
    if (b == 0) {
        int e0 = 2 * t, e1 = 2 * t + 1;
        int v0 = (e0 < nbkt) ? bcount[e0] : 0;
        int v1 = (e1 < nbkt) ? bcount[e1] : 0;
        int ps = v0 + v1;
        scanbuf[t] = ps;
        __syncthreads();
        for (int off = 1; off < 256; off <<= 1) {
            int x = (t >= off) ? scanbuf[t - off] : 0;
            __syncthreads();
            scanbuf[t] += x;
            __syncthreads();
        }
        int ex = scanbuf[t] - ps;
        if (e0 < nbkt) { boff[e0] = ex; bcur[e0] = ex; }
        if (e1 < nbkt) { boff[e1] = ex + v0; bcur[e1] = ex + v0; }
        if (t == 0) { boff[nbkt] = E; rowptr[N] = E; }
    } else if (b == 1) {
        int e0 = 2 * t, e1 = 2 * t + 1;
        int v0 = (e0 < G) ? counts[e0] : 0;
        int v1 = (e1 < G) ? counts[e1] : 0;
        int ps = v0 + v1;
        scanbuf[t] = ps;
        __syncthreads();
        for (int off = 1; off < 256; off <<= 1) {
            int x = (t >= off) ? scanbuf[t - off] : 0;
            __syncthreads();
            scanbuf[t] += x;
            __syncthreads();
        }
        int ex = scanbuf[t] - ps;
        if (e0 < G) gstart[e0] = ex;
        if (e1 < G) gstart[e1] = ex + v0;
        if (t == 255) gstart[G] = scanbuf[255];
    } else {
        int i = (b - 2) * 256 + t;
        if (i < N) {
            float md = fmaxf((float)(*maxd), 1.0f);
            x0[(size_t)i * HIDDIM + 101] = f2bf((float)depth[i] / md);
        }
    }
    __threadfence();
    grid.sync();

    // ---- phase 1: bucket scatter
    if (b < nbC) {
        int c0 = b * 4096;
        int ce = min(4096, E - c0);
        hist[t] = 0; hist[t + 256] = 0;
        __syncthreads();
        for (int i = t; i < ce; i += 256)
            atomicAdd(&hist[dst[c0 + i] >> 8], 1);
        __syncthreads();
        int h2a = hist[2 * t], h2b = hist[2 * t + 1];
        int ps = h2a + h2b;
        scanbuf[t] = ps;
        __syncthreads();
        for (int off = 1; off < 256; off <<= 1) {
            int x = (t >= off) ? scanbuf[t - off] : 0;
            __syncthreads();
            scanbuf[t] += x;
            __syncthreads();
        }
        int ex = scanbuf[t] - ps;
        ofs[2 * t] = ex;           cur[2 * t] = ex;
        ofs[2 * t + 1] = ex + h2a; cur[2 * t + 1] = ex + h2a;
        __syncthreads();
        for (int i = t; i < ce; i += 256) {
            int d = dst[c0 + i];
            int p = atomicAdd(&cur[d >> 8], 1);
            stage[p] = (uint32_t)src[c0 + i] | ((uint32_t)(d & 255) << 24);
            sbkt[p] = (unsigned short)(d >> 8);
        }
        __syncthreads();
        for (int bb = t; bb < nbkt; bb += 256) {
            int c = hist[bb];
            gbase[bb] = c ? atomicAdd(&bcur[bb], c) : 0;
        }
        __syncthreads();
        for (int j = t; j < ce; j += 256) {
            int bk = sbkt[j];
            ebuf[gbase[bk] + (j - ofs[bk])] = stage[j];
        }
    }
    __threadfence();
    grid.sync();

    // ---- phase 2: per-bucket CSR build (hist/ofs/cur reused as ldeg/lofs/lcur)
    if (b < nbkt) {
        int n0 = b << 8;
        int s = boff[b], e = boff[b + 1];
        hist[t] = 0;
        __syncthreads();
        for (int i = s + t; i < e; i += 256)
            atomicAdd(&hist[ebuf[i] >> 24], 1);
        __syncthreads();
        int v = hist[t];
        ofs[t] = v;
        __syncthreads();
        for (int off = 1; off < 256; off <<= 1) {
            int x = (t >= off) ? ofs[t - off] : 0;
            __syncthreads();
            ofs[t] += x;
            __syncthreads();
        }
        int excl = ofs[t] - v;
        int node = n0 + t;
        if (node < N) {
            rowptr[node] = s + excl;
            invd[node] = 1.0f / (float)max(v, 1);
        }
        cur[t] = excl;
        __syncthreads();
        for (int i = s + t; i < e; i += 256) {
            uint32_t p = ebuf[i];
            int slot = atomicAdd(&cur[p >> 24], 1);
            srcs[s + slot] = (int)(p & 0x00FFFFFFu);
        }
    }
}

// ---------------------------------------------------------------- aggregate: ax[d] = invd[d] * sum x[src[e]]
// one WAVE per dst, QUARTER-wave per edge. At compulsory traffic (r13: 179.5MB =
// 8 XCDs x touched-rows-once) and fabric-rate-limited ~3.6 TB/s -- do not touch.
__global__ void k_aggc(const uint4* __restrict__ x4, const int* __restrict__ rp,
                       const int* __restrict__ srcs, const float* __restrict__ invd,
                       uint4* __restrict__ axo, int N) {
    int t = threadIdx.x;
    int lane = t & 63;
    int q = lane >> 4;         // edge slot 0..3
    int cl = lane & 15;        // 16B chunk (cols cl*8 .. cl*8+7)
    int d = blockIdx.x * 4 + (t >> 6);
    if (d >= N) return;
    int s = rp[d], e = rp[d + 1];
    float a0 = 0.f, a1 = 0.f, a2 = 0.f, a3 = 0.f,
          a4 = 0.f, a5 = 0.f, a6 = 0.f, a7 = 0.f;
#define ACC8(u) { a0 += bflo(u.x); a1 += bfhi(u.x); a2 += bflo(u.y); a3 += bfhi(u.y); \
                  a4 += bflo(u.z); a5 += bfhi(u.z); a6 += bflo(u.w); a7 += bfhi(u.w); }
    for (int base = s; base < e; base += 64) {
        int m = min(64, e - base);
        int idx = (lane < m) ? srcs[base + lane] : 0;
        int j = 0;
        for (; j + 16 <= m; j += 16) {
            int i0 = __shfl(idx, j + q, 64);
            int i1 = __shfl(idx, j + 4 + q, 64);
            int i2 = __shfl(idx, j + 8 + q, 64);
            int i3 = __shfl(idx, j + 12 + q, 64);
            uint4 u0 = x4[(size_t)i0 * 16 + cl];
            uint4 u1 = x4[(size_t)i1 * 16 + cl];
            uint4 u2 = x4[(size_t)i2 * 16 + cl];
            uint4 u3 = x4[(size_t)i3 * 16 + cl];
            ACC8(u0); ACC8(u1); ACC8(u2); ACC8(u3);
        }
        for (; j + 4 <= m; j += 4) {
            int id = __shfl(idx, j + q, 64);
            uint4 u = x4[(size_t)id * 16 + cl];
            ACC8(u);
        }
        if (j < m) {
            int id = __shfl(idx, min(j + q, m - 1), 64);
            if (q < m - j) {
                uint4 u = x4[(size_t)id * 16 + cl];
                ACC8(u);
            }
        }
    }
#undef ACC8
    a0 += __shfl_down(a0, 32, 64); a1 += __shfl_down(a1, 32, 64);
    a2 += __shfl_down(a2, 32, 64); a3 += __shfl_down(a3, 32, 64);
    a4 += __shfl_down(a4, 32, 64); a5 += __shfl_down(a5, 32, 64);
    a6 += __shfl_down(a6, 32, 64); a7 += __shfl_down(a7, 32, 64);
    a0 += __shfl_down(a0, 16, 64); a1 += __shfl_down(a1, 16, 64);
    a2 += __shfl_down(a2, 16, 64); a3 += __shfl_down(a3, 16, 64);
    a4 += __shfl_down(a4, 16, 64); a5 += __shfl_down(a5, 16, 64);
    a6 += __shfl_down(a6, 16, 64); a7 += __shfl_down(a7, 16, 64);
    if (q == 0) {
        float iv = invd[d];
        uint4 o;
        o.x = pack2(a0 * iv, a1 * iv);
        o.y = pack2(a2 * iv, a3 * iv);
        o.z = pack2(a4 * iv, a5 * iv);
        o.w = pack2(a6 * iv, a7 * iv);
        axo[(size_t)d * 16 + cl] = o;
    }
}

// ---------------------------------------------------------------- dual-input bf16 MFMA GEMM (K=128 fixed):
// Xo[N,128] = relu(X @ Ws + AX @ Wn + bias_s + bias_n)
__global__ __launch_bounds__(256, 2) void k_gemm3(
    const unsigned short* __restrict__ X, const unsigned short* __restrict__ AX,
    const unsigned short* __restrict__ Wts, const unsigned short* __restrict__ Wtn,
    int N, const float* __restrict__ bias_s, const float* __restrict__ bias_n,
    unsigned short* __restrict__ Xo) {
    __shared__ unsigned short Bs[128 * LDSPAD];   // Ws^T, 34.8 KB
    __shared__ unsigned short Bn[128 * LDSPAD];   // Wn^T, 34.8 KB
    int t = threadIdx.x;
    int rowBase = blockIdx.x << 7;

    #pragma unroll
    for (int it = 0; it < 8; it++) {
        int idx = t + it * 256;
        int n = idx >> 4, seg = idx & 15;
        *(uint4*)&Bs[n * LDSPAD + seg * 8] = *(const uint4*)(Wts + n * HIDDIM + seg * 8);
        *(uint4*)&Bn[n * LDSPAD + seg * 8] = *(const uint4*)(Wtn + n * HIDDIM + seg * 8);
    }

    int lane = t & 63;
    int wv = t >> 6;
    int ml = lane & 15;
    int quad = lane >> 4;
    int m0 = wv * 32;

    const uint4* X4 = (const uint4*)X;
    const uint4* A4 = (const uint4*)AX;
    int gr0 = rowBase + m0 + ml;
    int gr1 = gr0 + 16;
    uint4 fx0[4], fx1[4], fa0[4], fa1[4];
    #pragma unroll
    for (int kt = 0; kt < 4; kt++) {
        uint4 z = make_uint4(0u, 0u, 0u, 0u);
        size_t o0 = (size_t)gr0 * 16 + kt * 4 + quad;
        size_t o1 = (size_t)gr1 * 16 + kt * 4 + quad;
        fx0[kt] = (gr0 < N) ? X4[o0] : z;
        fx1[kt] = (gr1 < N) ? X4[o1] : z;
        fa0[kt] = (gr0 < N) ? A4[o0] : z;
        fa1[kt] = (gr1 < N) ? A4[o1] : z;
    }
    __syncthreads();

    f32x4 acc[2][8];
    #pragma unroll
    for (int i = 0; i < 2; i++)
        #pragma unroll
        for (int j = 0; j < 8; j++) acc[i][j] = (f32x4){0.f, 0.f, 0.f, 0.f};

    #pragma unroll
    for (int kt = 0; kt < 4; kt++) {
        int ko = kt * 32 + quad * 8;
        short8 x0f = *(short8*)&fx0[kt];
        short8 x1f = *(short8*)&fx1[kt];
        short8 a0f = *(short8*)&fa0[kt];
        short8 a1f = *(short8*)&fa1[kt];
        #pragma unroll
        for (int nt = 0; nt < 8; nt++) {
            short8 bs = *(const short8*)&Bs[(nt * 16 + ml) * LDSPAD + ko];
            short8 bn = *(const short8*)&Bn[(nt * 16 + ml) * LDSPAD + ko];
            acc[0][nt] = __builtin_amdgcn_mfma_f32_16x16x32_bf16(x0f, bs, acc[0][nt], 0, 0, 0);
            acc[1][nt] = __builtin_amdgcn_mfma_f32_16x16x32_bf16(x1f, bs, acc[1][nt], 0, 0, 0);
            acc[0][nt] = __builtin_amdgcn_mfma_f32_16x16x32_bf16(a0f, bn, acc[0][nt], 0, 0, 0);
            acc[1][nt] = __builtin_amdgcn_mfma_f32_16x16x32_bf16(a1f, bn, acc[1][nt], 0, 0, 0);
        }
    }

    float bsum[8];
    #pragma unroll
    for (int nt = 0; nt < 8; nt++) {
        int col = nt * 16 + ml;
        bsum[nt] = bias_s[col] + bias_n[col];
    }

    __syncthreads();
    #pragma unroll
    for (int mt = 0; mt < 2; mt++) {
        int lrow0 = m0 + mt * 16 + quad * 4;
        #pragma unroll
        for (int r = 0; r < 4; r++)
            #pragma unroll
            for (int nt = 0; nt < 8; nt++)
                Bs[(lrow0 + r) * LDSPAD + nt * 16 + ml] =
                    f2bf(fmaxf(acc[mt][nt][r] + bsum[nt], 0.f));
    }
    __syncthreads();
    #pragma unroll
    for (int it = 0; it < 8; it++) {
        int idx = t + it * 256;
        int r = idx >> 4, seg = idx & 15;
        int gr = rowBase + r;
        if (gr < N)
            *(uint4*)(Xo + (size_t)gr * HIDDIM + seg * 8) = *(const uint4*)&Bs[r * LDSPAD + seg * 8];
    }
}

// ---------------------------------------------------------------- fused mean-pool + heads (256 thr/graph)
__global__ void k_poolhead(const uint32_t* __restrict__ x, const int* __restrict__ gstart,
                           const int* __restrict__ counts,
                           const float* __restrict__ Wr, const float* __restrict__ br,
                           const float* __restrict__ Wc, const float* __restrict__ bc,
                           float* __restrict__ out, int G) {
    __shared__ float red[3][128];
    __shared__ float rowf[128];
    int gr = blockIdx.x, t = threadIdx.x;
    int wv = t >> 6, lane = t & 63;
    int half = lane >> 5, cl = lane & 31;
    int s = gstart[gr], e = gstart[gr + 1];
    const uint2* x2 = (const uint2*)x;
    float a0 = 0.f, a1 = 0.f, a2 = 0.f, a3 = 0.f;
    for (int r0 = s + wv * 2 + half; r0 < e; r0 += 32) {
        uint2 u0 = x2[(size_t)r0 * 32 + cl];
        int r1 = r0 + 8, r2 = r0 + 16, r3 = r0 + 24;
        uint2 u1 = make_uint2(0u, 0u), u2 = make_uint2(0u, 0u), u3 = make_uint2(0u, 0u);
        if (r1 < e) u1 = x2[(size_t)r1 * 32 + cl];
        if (r2 < e) u2 = x2[(size_t)r2 * 32 + cl];
        if (r3 < e) u3 = x2[(size_t)r3 * 32 + cl];
        a0 += bflo(u0.x); a1 += bfhi(u0.x); a2 += bflo(u0.y); a3 += bfhi(u0.y);
        a0 += bflo(u1.x); a1 += bfhi(u1.x); a2 += bflo(u1.y); a3 += bfhi(u1.y);
        a0 += bflo(u2.x); a1 += bfhi(u2.x); a2 += bflo(u2.y); a3 += bfhi(u2.y);
        a0 += bflo(u3.x); a1 += bfhi(u3.x); a2 += bflo(u3.y); a3 += bfhi(u3.y);
    }
    a0 += __shfl_down(a0, 32, 64);
    a1 += __shfl_down(a1, 32, 64);
    a2 += __shfl_down(a2, 32, 64);
    a3 += __shfl_down(a3, 32, 64);
    if (half == 0 && wv > 0) {
        red[wv - 1][cl * 4 + 0] = a0;
        red[wv - 1][cl * 4 + 1] = a1;
        red[wv - 1][cl * 4 + 2] = a2;
        red[wv - 1][cl * 4 + 3] = a3;
    }
    __syncthreads();
    if (wv == 0 && half == 0) {
        a0 += red[0][cl * 4 + 0] + red[1][cl * 4 + 0] + red[2][cl * 4 + 0];
        a1 += red[0][cl * 4 + 1] + red[1][cl * 4 + 1] + red[2][cl * 4 + 1];
        a2 += red[0][cl * 4 + 2] + red[1][cl * 4 + 2] + red[2][cl * 4 + 2];
        a3 += red[0][cl * 4 + 3] + red[1][cl * 4 + 3] + red[2][cl * 4 + 3];
        float inv = 1.0f / fmaxf((float)counts[gr], 1.0f);
        rowf[cl * 4 + 0] = a0 * inv;
        rowf[cl * 4 + 1] = a1 * inv;
        rowf[cl * 4 + 2] = a2 * inv;
        rowf[cl * 4 + 3] = a3 * inv;
    }
    __syncthreads();
    if (t == 0) {
        float s2 = 0.f;
        for (int k = 0; k < 128; k++) s2 += rowf[k] * Wr[k];
        out[gr] = s2 + br[0];
    } else if (t <= 10) {
        int j = t - 1;
        float s2 = 0.f;
        for (int k = 0; k < 128; k++) s2 += rowf[k] * Wc[k * 10 + j];
        out[G + gr * 10 + j] = s2 + bc[j];
    }
}

// ================================================================ host
extern "C" void kernel_launch(void* const* d_in, const int* in_sizes, int n_in,
                              void* d_out, int out_size, void* d_ws, size_t ws_size,
                              hipStream_t stream) {
    const int*   nt    = (const int*)d_in[0];
    const int*   ih    = (const int*)d_in[1];
    const float* flags = (const float*)d_in[2];
    const int*   depth = (const int*)d_in[3];
    const int*   eidx  = (const int*)d_in[4];
    const int*   batch = (const int*)d_in[5];
    const float* embN  = (const float*)d_in[6];
    const float* embI  = (const float*)d_in[7];
    const float* Ws0   = (const float*)d_in[8];
    const float* bs0   = (const float*)d_in[9];
    const float* Wn0   = (const float*)d_in[10];
    const float* bn0   = (const float*)d_in[11];
    const float* Ws1   = (const float*)d_in[12];
    const float* bs1   = (const float*)d_in[13];
    const float* Wn1   = (const float*)d_in[14];
    const float* bn1   = (const float*)d_in[15];
    const float* Wr    = (const float*)d_in[16];
    const float* br    = (const float*)d_in[17];
    const float* Wc    = (const float*)d_in[18];
    const float* bc    = (const float*)d_in[19];
    float* out = (float*)d_out;

    const int N  = in_sizes[0];
    const int E  = in_sizes[4] / 2;
    const int K0 = in_sizes[8] / HIDDIM;   // 102
    const int G  = out_size / 11;          // 512
    const int* esrc = eidx;
    const int* edst = eidx + E;
    const int NBKT = (N + 255) >> 8;       // 391

    // ---- workspace carve-up
    char* w = (char*)d_ws;
    const size_t NH = (size_t)N * HIDDIM * sizeof(unsigned short);
    unsigned short* bufA  = (unsigned short*)(w);           // x0, later x2
    unsigned short* bufB  = (unsigned short*)(w + NH);      // x1
    unsigned short* bufAX = (unsigned short*)(w + 2 * NH);  // ax (both layers)
    char* p = w + 3 * NH;
    unsigned short* Wt = (unsigned short*)p; p += (size_t)4 * HIDDIM * HIDDIM * 2;  // 128KB
    uint32_t* ebuf = (uint32_t*)p;   p += (size_t)E * 4;
    int* srcs   = (int*)p;           p += (size_t)E * 4;
    int* rowptr = (int*)p;           p += (size_t)(N + 1) * 4;
    float* invd = (float*)p;         p += (size_t)N * 4;
    int* gstart = (int*)p;           p += (size_t)(G + 1) * 4;
    int* boff   = (int*)p;           p += (size_t)(NBKT_MAX + 1) * 4;
    int* bcur   = (int*)p;           p += (size_t)NBKT_MAX * 4;
    // zeroed block: bcount, counts, maxd (contiguous)
    int* bcount = (int*)p;           p += (size_t)NBKT_MAX * 4;
    int* counts = (int*)p;           p += (size_t)G * 4;
    int* maxd   = (int*)p;           p += 4;
    const size_t zero_bytes = (size_t)(NBKT_MAX + G + 1) * 4;
    (void)n_in; (void)ws_size;

    const int nbC = (E + 4095) / 4096;               // 391
    const int nbN = (N + 255) / 256;                 // 391
    const int nbF = ((size_t)N * 16 + 255) / 256;    // 6250 (16 thr/node)
    const int nbG2 = (N + 127) / 128;
    const int nbA = (N + 3) / 4;

    hipMemsetAsync(bcount, 0, zero_bytes, stream);

    // fused prep: feat | bcount | nodestats | wt
    k_prep<<<nbF + nbC + nbN + 256, 256, 0, stream>>>(
        nt, ih, flags, depth, embN, embI, edst, batch,
        Wn0, Ws0, Wn1, Ws1, K0, N, E, G,
        bufA, Wt, bcount, counts, maxd, nbF, nbC, nbN);

    // cooperative CSR: scans + depth col | scatter | build
    {
        const int nbD256 = (N + 255) / 256;
        int nbCoop = nbC;
        if (NBKT > nbCoop) nbCoop = NBKT;
        if (2 + nbD256 > nbCoop) nbCoop = 2 + nbD256;
        const int* a_src = esrc; const int* a_dst = edst;
        const int* a_bcount = bcount;
        int* a_boff = boff; int* a_bcur = bcur; int* a_rowptr = rowptr;
        const int* a_counts = counts; int* a_gstart = gstart;
        const int* a_depth = depth; const int* a_maxd = maxd;
        unsigned short* a_x0 = bufA;
        uint32_t* a_ebuf = ebuf; float* a_invd = invd; int* a_srcs = srcs;
        int v_nbkt = NBKT, v_N = N, v_E = E, v_G = G, v_nbC = nbC;
        void* cargs[] = { &a_src, &a_dst, &a_bcount, &a_boff, &a_bcur, &a_rowptr,
                          &a_counts, &a_gstart, &a_depth, &a_maxd, &a_x0,
                          &a_ebuf, &a_invd, &a_srcs,
                          &v_nbkt, &v_N, &v_E, &v_G, &v_nbC };
        hipLaunchCooperativeKernel((void*)k_csr, dim3(nbCoop), dim3(256),
                                   cargs, 0, stream);
    }

    const unsigned short* Wt_n0 = Wt;
    const unsigned short* Wt_s0 = Wt + 1 * HIDDIM * HIDDIM;
    const unsigned short* Wt_n1 = Wt + 2 * HIDDIM * HIDDIM;
    const unsigned short* Wt_s1 = Wt + 3 * HIDDIM * HIDDIM;

    // layer 0: ax = invd*(A x0) ; x1 = relu(x0@Ws0 + ax@Wn0 + b)
    k_aggc<<<nbA, 256, 0, stream>>>((const uint4*)bufA, rowptr, srcs, invd,
                                    (uint4*)bufAX, N);
    k_gemm3<<<nbG2, 256, 0, stream>>>(bufA, bufAX, Wt_s0, Wt_n0, N, bs0, bn0, bufB);

    // layer 1: ax = invd*(A x1) ; x2 = relu(x1@Ws1 + ax@Wn1 + b)  (into bufA)
    k_aggc<<<nbA, 256, 0, stream>>>((const uint4*)bufB, rowptr, srcs, invd,
                                    (uint4*)bufAX, N);
    k_gemm3<<<nbG2, 256, 0, stream>>>(bufB, bufAX, Wt_s1, Wt_n1, N, bs1, bn1, bufA);

    // fused pool + heads
    k_poolhead<<<G, 256, 0, stream>>>((const uint32_t*)bufA, gstart, counts,
                                      Wr, br, Wc, bc, out, G);
}

// Round 15
// 339.879 us; speedup vs baseline: 1.6318x; 1.6318x over previous
//
#include <hip/hip_runtime.h>
#include <cstdint>
#include <cstddef>

#define HIDDIM 128
#define NGRAPH_MAX 512
#define LDSPAD 136   // 128 + 8 bf16 pad: row stride 272B (16B-aligned, bank-conflict-free frag reads)
#define NBKT_MAX 512 // coarse buckets of 256 nodes (dst>>8); N<=131072

// r15: reverted r14's cooperative CSR fusion (grid.sync across 393 blocks / 8 XCDs
// cost 225µs at 0.8% VALUBusy -- launch boundaries are far cheaper than coop sync
// for short phases). Keeps r13 structure + the one good piece of r14: parallel
// per-element bscatter flush via bucket-id LDS array (r13 regression was a serial
// per-bucket copy). aggc at compulsory traffic (179.5MB = 8 XCDs x touched-once),
// fabric-limited ~3.6 TB/s -- untouched.

using short8 = __attribute__((ext_vector_type(8))) short;
using f32x4  = __attribute__((ext_vector_type(4))) float;

__device__ __forceinline__ unsigned short f2bf(float x) {
    union { float f; uint32_t u; } v; v.f = x;
    uint32_t r = v.u + 0x7fffu + ((v.u >> 16) & 1u);   // RNE
    return (unsigned short)(r >> 16);
}
__device__ __forceinline__ uint32_t pack2(float a, float b) {
    return (uint32_t)f2bf(a) | ((uint32_t)f2bf(b) << 16);
}
__device__ __forceinline__ float bflo(uint32_t u) { return __uint_as_float(u << 16); }
__device__ __forceinline__ float bfhi(uint32_t u) { return __uint_as_float(u & 0xffff0000u); }

// ---------------------------------------------------------------- fused prep: feat | bcount | nodestats | wt
// block ranges: [0,nbF) feat(16 thr/node) ; [nbF,+nbC) bcount ; [+nbN) nodestats ; [+256) wt
__global__ void k_prep(const int* __restrict__ nt, const int* __restrict__ ih,
                       const float* __restrict__ flags, const int* __restrict__ depth,
                       const float* __restrict__ embN, const float* __restrict__ embI,
                       const int* __restrict__ edst, const int* __restrict__ batch,
                       const float* __restrict__ Wn0, const float* __restrict__ Ws0,
                       const float* __restrict__ Wn1, const float* __restrict__ Ws1,
                       int K0, int N, int E, int G,
                       unsigned short* __restrict__ x0, unsigned short* __restrict__ Wt,
                       int* __restrict__ bcount, int* __restrict__ counts,
                       int* __restrict__ maxd,
                       int nbF, int nbC, int nbN) {
    __shared__ int hist[NBKT_MAX];
    __shared__ int red[256];
    int b = blockIdx.x, t = threadIdx.x;
    if (b < nbF) {
        // ---- node features: 16 threads/node, one uint4 (8 bf16 cols) each
        int idx = b * 256 + t;
        int i = idx >> 4;
        int seg = idx & 15;
        if (i >= N) return;
        uint4 o = make_uint4(0u, 0u, 0u, 0u);
        if (seg < 8) {
            const float4* r = (const float4*)(embN + (size_t)nt[i] * 64 + seg * 8);
            float4 v0 = r[0], v1 = r[1];
            o.x = pack2(v0.x, v0.y); o.y = pack2(v0.z, v0.w);
            o.z = pack2(v1.x, v1.y); o.w = pack2(v1.z, v1.w);
        } else if (seg < 12) {
            const float4* r = (const float4*)(embI + (size_t)ih[i] * 32 + (seg - 8) * 8);
            float4 v0 = r[0], v1 = r[1];
            o.x = pack2(v0.x, v0.y); o.y = pack2(v0.z, v0.w);
            o.z = pack2(v1.x, v1.y); o.w = pack2(v1.z, v1.w);
        } else if (seg == 12) {
            // cols 96..103: 5 flags, col101=0 (depth written by k_scan2x), 102..103=0
            const float* fp = flags + (size_t)i * 5;
            o.x = pack2(fp[0], fp[1]);
            o.y = pack2(fp[2], fp[3]);
            o.z = pack2(fp[4], 0.f);
        } // seg 13..15: zeros
        *(uint4*)(x0 + (size_t)i * HIDDIM + seg * 8) = o;
    } else if (b < nbF + nbC) {
        // ---- edge bucket histogram
        hist[t] = 0; hist[t + 256] = 0;
        __syncthreads();
        int c0 = (b - nbF) * 4096;
        int ce = min(4096, E - c0);
        for (int i = t; i < ce; i += 256)
            atomicAdd(&hist[edst[c0 + i] >> 8], 1);
        __syncthreads();
        for (int bb = t; bb < NBKT_MAX; bb += 256)
            if (hist[bb]) atomicAdd(&bcount[bb], hist[bb]);
    } else if (b < nbF + nbC + nbN) {
        // ---- graph counts + max depth
        for (int g = t; g < G; g += 256) hist[g] = 0;
        __syncthreads();
        int i = (b - nbF - nbC) * 256 + t;
        int d = 0;
        if (i < N) {
            atomicAdd(&hist[batch[i]], 1);
            d = depth[i];
        }
        red[t] = d;
        __syncthreads();
        for (int off = 128; off > 0; off >>= 1) {
            if (t < off) red[t] = max(red[t], red[t + off]);
            __syncthreads();
        }
        if (t == 0) atomicMax(maxd, red[0]);
        for (int g = t; g < G; g += 256)
            if (hist[g]) atomicAdd(&counts[g], hist[g]);
    } else {
        // ---- weight pre-transpose: Wt[mat][n][k] bf16, K zero-padded to 128
        int idx = (b - nbF - nbC - nbN) * 256 + t;   // 65536 total
        int mat = idx >> 14;
        int rem = idx & 16383;
        int n = rem >> 7, k = rem & 127;
        const float* W = (mat == 0) ? Wn0 : (mat == 1) ? Ws0 : (mat == 2) ? Wn1 : Ws1;
        int K = (mat < 2) ? K0 : HIDDIM;
        Wt[(size_t)mat * HIDDIM * HIDDIM + n * HIDDIM + k] =
            (k < K) ? f2bf(W[(size_t)k * HIDDIM + n]) : (unsigned short)0;
    }
}

// ---------------------------------------------------------------- fused scans + depth column (512 thr)
__global__ void k_scan2x(const int* __restrict__ bcount, int* __restrict__ boff,
                         int* __restrict__ bcur, int* __restrict__ rowptr,
                         const int* __restrict__ counts, int* __restrict__ gstart,
                         const int* __restrict__ depth, const int* __restrict__ maxd,
                         unsigned short* __restrict__ x0,
                         int nbkt, int N, int E, int G) {
    __shared__ int sd[512];
    int b = blockIdx.x, t = threadIdx.x;
    if (b == 0) {
        int v = (t < nbkt) ? bcount[t] : 0;
        sd[t] = v;
        __syncthreads();
        for (int off = 1; off < 512; off <<= 1) {
            int x = (t >= off) ? sd[t - off] : 0;
            __syncthreads();
            sd[t] += x;
            __syncthreads();
        }
        if (t < nbkt) { boff[t] = sd[t] - v; bcur[t] = sd[t] - v; }
        if (t == 0) { boff[nbkt] = E; rowptr[N] = E; }
    } else if (b == 1) {
        int v = (t < G) ? counts[t] : 0;
        sd[t] = v;
        __syncthreads();
        for (int off = 1; off < 512; off <<= 1) {
            int x = (t >= off) ? sd[t - off] : 0;
            __syncthreads();
            sd[t] += x;
            __syncthreads();
        }
        if (t < G) gstart[t] = sd[t] - v;
        if (t == G - 1) gstart[G] = sd[t];
    } else {
        int i = (b - 2) * 512 + t;
        if (i < N) {
            float md = fmaxf((float)(*maxd), 1.0f);
            x0[(size_t)i * HIDDIM + 101] = f2bf((float)depth[i] / md);
        }
    }
}

// ---------------------------------------------------------------- bucket scatter: LDS-sort 4096-edge chunk,
// per-(block,bucket) global reservation, PARALLEL per-element flush via sbkt[]
// bucket-id array (int, conflict-benign). ebuf packed uint32 (src | dlow<<24).
__global__ void k_bscatter(const int* __restrict__ src, const int* __restrict__ dst,
                           int* __restrict__ bcur, uint32_t* __restrict__ ebuf, int E, int nbkt) {
    __shared__ uint32_t stage[4096];    // 16 KB
    __shared__ int sbkt[4096];          // 16 KB (bucket id per staged slot)
    __shared__ int hist[NBKT_MAX];
    __shared__ int ofs[NBKT_MAX];
    __shared__ int cur[NBKT_MAX];
    __shared__ int gbase[NBKT_MAX];
    __shared__ int scanbuf[256];
    int t = threadIdx.x;
    int c0 = blockIdx.x * 4096;
    int ce = min(4096, E - c0);

    hist[t] = 0; hist[t + 256] = 0;
    __syncthreads();
    for (int i = t; i < ce; i += 256)
        atomicAdd(&hist[dst[c0 + i] >> 8], 1);
    __syncthreads();
    int h2a = hist[2 * t], h2b = hist[2 * t + 1];
    int ps = h2a + h2b;
    scanbuf[t] = ps;
    __syncthreads();
    for (int off = 1; off < 256; off <<= 1) {
        int x = (t >= off) ? scanbuf[t - off] : 0;
        __syncthreads();
        scanbuf[t] += x;
        __syncthreads();
    }
    int ex = scanbuf[t] - ps;
    ofs[2 * t] = ex;           cur[2 * t] = ex;
    ofs[2 * t + 1] = ex + h2a; cur[2 * t + 1] = ex + h2a;
    __syncthreads();
    for (int i = t; i < ce; i += 256) {
        int d = dst[c0 + i];
        int p = atomicAdd(&cur[d >> 8], 1);
        stage[p] = (uint32_t)src[c0 + i] | ((uint32_t)(d & 255) << 24);
        sbkt[p] = d >> 8;
    }
    __syncthreads();
    for (int b = t; b < nbkt; b += 256) {
        int c = hist[b];
        gbase[b] = c ? atomicAdd(&bcur[b], c) : 0;
    }
    __syncthreads();
    for (int j = t; j < ce; j += 256) {
        int bk = sbkt[j];
        ebuf[gbase[bk] + (j - ofs[bk])] = stage[j];
    }
}

// ---------------------------------------------------------------- per-bucket CSR build: deg, rowptr, invd, srcs
__global__ void k_build(const uint32_t* __restrict__ ebuf, const int* __restrict__ boff,
                        int* __restrict__ rowptr, float* __restrict__ invd,
                        int* __restrict__ srcs, int N) {
    __shared__ int ldeg[256];
    __shared__ int lofs[256];
    __shared__ int lcur[256];
    int b = blockIdx.x, t = threadIdx.x;
    int n0 = b << 8;
    int s = boff[b], e = boff[b + 1];
    ldeg[t] = 0;
    __syncthreads();
    for (int i = s + t; i < e; i += 256)
        atomicAdd(&ldeg[ebuf[i] >> 24], 1);
    __syncthreads();
    int v = ldeg[t];
    lofs[t] = v;
    __syncthreads();
    for (int off = 1; off < 256; off <<= 1) {
        int x = (t >= off) ? lofs[t - off] : 0;
        __syncthreads();
        lofs[t] += x;
        __syncthreads();
    }
    int excl = lofs[t] - v;
    int node = n0 + t;
    if (node < N) {
        rowptr[node] = s + excl;
        invd[node] = 1.0f / (float)max(v, 1);
    }
    lcur[t] = excl;
    __syncthreads();
    for (int i = s + t; i < e; i += 256) {
        uint32_t p = ebuf[i];
        int slot = atomicAdd(&lcur[p >> 24], 1);
        srcs[s + slot] = (int)(p & 0x00FFFFFFu);
    }
}

// ---------------------------------------------------------------- aggregate: ax[d] = invd[d] * sum x[src[e]]
// one WAVE per dst, QUARTER-wave per edge. At compulsory traffic (r13: 179.5MB =
// 8 XCDs x touched-rows-once), fabric-limited ~3.6 TB/s -- do not touch.
__global__ void k_aggc(const uint4* __restrict__ x4, const int* __restrict__ rp,
                       const int* __restrict__ srcs, const float* __restrict__ invd,
                       uint4* __restrict__ axo, int N) {
    int t = threadIdx.x;
    int lane = t & 63;
    int q = lane >> 4;         // edge slot 0..3
    int cl = lane & 15;        // 16B chunk (cols cl*8 .. cl*8+7)
    int d = blockIdx.x * 4 + (t >> 6);
    if (d >= N) return;
    int s = rp[d], e = rp[d + 1];
    float a0 = 0.f, a1 = 0.f, a2 = 0.f, a3 = 0.f,
          a4 = 0.f, a5 = 0.f, a6 = 0.f, a7 = 0.f;
#define ACC8(u) { a0 += bflo(u.x); a1 += bfhi(u.x); a2 += bflo(u.y); a3 += bfhi(u.y); \
                  a4 += bflo(u.z); a5 += bfhi(u.z); a6 += bflo(u.w); a7 += bfhi(u.w); }
    for (int base = s; base < e; base += 64) {
        int m = min(64, e - base);
        int idx = (lane < m) ? srcs[base + lane] : 0;
        int j = 0;
        for (; j + 16 <= m; j += 16) {     // 16 edges: 4 uint4 loads in flight/lane
            int i0 = __shfl(idx, j + q, 64);
            int i1 = __shfl(idx, j + 4 + q, 64);
            int i2 = __shfl(idx, j + 8 + q, 64);
            int i3 = __shfl(idx, j + 12 + q, 64);
            uint4 u0 = x4[(size_t)i0 * 16 + cl];
            uint4 u1 = x4[(size_t)i1 * 16 + cl];
            uint4 u2 = x4[(size_t)i2 * 16 + cl];
            uint4 u3 = x4[(size_t)i3 * 16 + cl];
            ACC8(u0); ACC8(u1); ACC8(u2); ACC8(u3);
        }
        for (; j + 4 <= m; j += 4) {
            int id = __shfl(idx, j + q, 64);
            uint4 u = x4[(size_t)id * 16 + cl];
            ACC8(u);
        }
        if (j < m) {                       // 1..3 leftover edges
            int id = __shfl(idx, min(j + q, m - 1), 64);
            if (q < m - j) {
                uint4 u = x4[(size_t)id * 16 + cl];
                ACC8(u);
            }
        }
    }
#undef ACC8
    a0 += __shfl_down(a0, 32, 64); a1 += __shfl_down(a1, 32, 64);
    a2 += __shfl_down(a2, 32, 64); a3 += __shfl_down(a3, 32, 64);
    a4 += __shfl_down(a4, 32, 64); a5 += __shfl_down(a5, 32, 64);
    a6 += __shfl_down(a6, 32, 64); a7 += __shfl_down(a7, 32, 64);
    a0 += __shfl_down(a0, 16, 64); a1 += __shfl_down(a1, 16, 64);
    a2 += __shfl_down(a2, 16, 64); a3 += __shfl_down(a3, 16, 64);
    a4 += __shfl_down(a4, 16, 64); a5 += __shfl_down(a5, 16, 64);
    a6 += __shfl_down(a6, 16, 64); a7 += __shfl_down(a7, 16, 64);
    if (q == 0) {
        float iv = invd[d];
        uint4 o;
        o.x = pack2(a0 * iv, a1 * iv);
        o.y = pack2(a2 * iv, a3 * iv);
        o.z = pack2(a4 * iv, a5 * iv);
        o.w = pack2(a6 * iv, a7 * iv);
        axo[(size_t)d * 16 + cl] = o;
    }
}

// ---------------------------------------------------------------- dual-input bf16 MFMA GEMM (K=128 fixed):
// Xo[N,128] = relu(X @ Ws + AX @ Wn + bias_s + bias_n)   (bf16 out, fp32 acc)
__global__ __launch_bounds__(256, 2) void k_gemm3(
    const unsigned short* __restrict__ X, const unsigned short* __restrict__ AX,
    const unsigned short* __restrict__ Wts, const unsigned short* __restrict__ Wtn,
    int N, const float* __restrict__ bias_s, const float* __restrict__ bias_n,
    unsigned short* __restrict__ Xo) {
    __shared__ unsigned short Bs[128 * LDSPAD];   // Ws^T, 34.8 KB
    __shared__ unsigned short Bn[128 * LDSPAD];   // Wn^T, 34.8 KB
    int t = threadIdx.x;
    int rowBase = blockIdx.x << 7;

    #pragma unroll
    for (int it = 0; it < 8; it++) {
        int idx = t + it * 256;
        int n = idx >> 4, seg = idx & 15;
        *(uint4*)&Bs[n * LDSPAD + seg * 8] = *(const uint4*)(Wts + n * HIDDIM + seg * 8);
        *(uint4*)&Bn[n * LDSPAD + seg * 8] = *(const uint4*)(Wtn + n * HIDDIM + seg * 8);
    }

    int lane = t & 63;
    int wv = t >> 6;          // 4 waves -> rows [wv*32, wv*32+32)
    int ml = lane & 15;
    int quad = lane >> 4;
    int m0 = wv * 32;

    // hoisted A-frags from both inputs (16 independent uint4 loads)
    const uint4* X4 = (const uint4*)X;
    const uint4* A4 = (const uint4*)AX;
    int gr0 = rowBase + m0 + ml;
    int gr1 = gr0 + 16;
    uint4 fx0[4], fx1[4], fa0[4], fa1[4];
    #pragma unroll
    for (int kt = 0; kt < 4; kt++) {
        uint4 z = make_uint4(0u, 0u, 0u, 0u);
        size_t o0 = (size_t)gr0 * 16 + kt * 4 + quad;
        size_t o1 = (size_t)gr1 * 16 + kt * 4 + quad;
        fx0[kt] = (gr0 < N) ? X4[o0] : z;
        fx1[kt] = (gr1 < N) ? X4[o1] : z;
        fa0[kt] = (gr0 < N) ? A4[o0] : z;
        fa1[kt] = (gr1 < N) ? A4[o1] : z;
    }
    __syncthreads();

    f32x4 acc[2][8];
    #pragma unroll
    for (int i = 0; i < 2; i++)
        #pragma unroll
        for (int j = 0; j < 8; j++) acc[i][j] = (f32x4){0.f, 0.f, 0.f, 0.f};

    #pragma unroll
    for (int kt = 0; kt < 4; kt++) {
        int ko = kt * 32 + quad * 8;
        short8 x0f = *(short8*)&fx0[kt];
        short8 x1f = *(short8*)&fx1[kt];
        short8 a0f = *(short8*)&fa0[kt];
        short8 a1f = *(short8*)&fa1[kt];
        #pragma unroll
        for (int nt = 0; nt < 8; nt++) {
            short8 bs = *(const short8*)&Bs[(nt * 16 + ml) * LDSPAD + ko];
            short8 bn = *(const short8*)&Bn[(nt * 16 + ml) * LDSPAD + ko];
            acc[0][nt] = __builtin_amdgcn_mfma_f32_16x16x32_bf16(x0f, bs, acc[0][nt], 0, 0, 0);
            acc[1][nt] = __builtin_amdgcn_mfma_f32_16x16x32_bf16(x1f, bs, acc[1][nt], 0, 0, 0);
            acc[0][nt] = __builtin_amdgcn_mfma_f32_16x16x32_bf16(a0f, bn, acc[0][nt], 0, 0, 0);
            acc[1][nt] = __builtin_amdgcn_mfma_f32_16x16x32_bf16(a1f, bn, acc[1][nt], 0, 0, 0);
        }
    }

    float bsum[8];
    #pragma unroll
    for (int nt = 0; nt < 8; nt++) {
        int col = nt * 16 + ml;
        bsum[nt] = bias_s[col] + bias_n[col];
    }

    // ---- epilogue: Bs is dead; relu + LDS round-trip -> coalesced stores
    __syncthreads();
    #pragma unroll
    for (int mt = 0; mt < 2; mt++) {
        int lrow0 = m0 + mt * 16 + quad * 4;
        #pragma unroll
        for (int r = 0; r < 4; r++)
            #pragma unroll
            for (int nt = 0; nt < 8; nt++)
                Bs[(lrow0 + r) * LDSPAD + nt * 16 + ml] =
                    f2bf(fmaxf(acc[mt][nt][r] + bsum[nt], 0.f));
    }
    __syncthreads();
    #pragma unroll
    for (int it = 0; it < 8; it++) {
        int idx = t + it * 256;
        int r = idx >> 4, seg = idx & 15;
        int gr = rowBase + r;
        if (gr < N)
            *(uint4*)(Xo + (size_t)gr * HIDDIM + seg * 8) = *(const uint4*)&Bs[r * LDSPAD + seg * 8];
    }
}

// ---------------------------------------------------------------- fused mean-pool + heads (256 thr/graph)
__global__ void k_poolhead(const uint32_t* __restrict__ x, const int* __restrict__ gstart,
                           const int* __restrict__ counts,
                           const float* __restrict__ Wr, const float* __restrict__ br,
                           const float* __restrict__ Wc, const float* __restrict__ bc,
                           float* __restrict__ out, int G) {
    __shared__ float red[3][128];
    __shared__ float rowf[128];
    int gr = blockIdx.x, t = threadIdx.x;
    int wv = t >> 6, lane = t & 63;
    int half = lane >> 5, cl = lane & 31;
    int s = gstart[gr], e = gstart[gr + 1];
    const uint2* x2 = (const uint2*)x;
    float a0 = 0.f, a1 = 0.f, a2 = 0.f, a3 = 0.f;
    for (int r0 = s + wv * 2 + half; r0 < e; r0 += 32) {
        uint2 u0 = x2[(size_t)r0 * 32 + cl];
        int r1 = r0 + 8, r2 = r0 + 16, r3 = r0 + 24;
        uint2 u1 = make_uint2(0u, 0u), u2 = make_uint2(0u, 0u), u3 = make_uint2(0u, 0u);
        if (r1 < e) u1 = x2[(size_t)r1 * 32 + cl];
        if (r2 < e) u2 = x2[(size_t)r2 * 32 + cl];
        if (r3 < e) u3 = x2[(size_t)r3 * 32 + cl];
        a0 += bflo(u0.x); a1 += bfhi(u0.x); a2 += bflo(u0.y); a3 += bfhi(u0.y);
        a0 += bflo(u1.x); a1 += bfhi(u1.x); a2 += bflo(u1.y); a3 += bfhi(u1.y);
        a0 += bflo(u2.x); a1 += bfhi(u2.x); a2 += bflo(u2.y); a3 += bfhi(u2.y);
        a0 += bflo(u3.x); a1 += bfhi(u3.x); a2 += bflo(u3.y); a3 += bfhi(u3.y);
    }
    a0 += __shfl_down(a0, 32, 64);
    a1 += __shfl_down(a1, 32, 64);
    a2 += __shfl_down(a2, 32, 64);
    a3 += __shfl_down(a3, 32, 64);
    if (half == 0 && wv > 0) {
        red[wv - 1][cl * 4 + 0] = a0;
        red[wv - 1][cl * 4 + 1] = a1;
        red[wv - 1][cl * 4 + 2] = a2;
        red[wv - 1][cl * 4 + 3] = a3;
    }
    __syncthreads();
    if (wv == 0 && half == 0) {
        a0 += red[0][cl * 4 + 0] + red[1][cl * 4 + 0] + red[2][cl * 4 + 0];
        a1 += red[0][cl * 4 + 1] + red[1][cl * 4 + 1] + red[2][cl * 4 + 1];
        a2 += red[0][cl * 4 + 2] + red[1][cl * 4 + 2] + red[2][cl * 4 + 2];
        a3 += red[0][cl * 4 + 3] + red[1][cl * 4 + 3] + red[2][cl * 4 + 3];
        float inv = 1.0f / fmaxf((float)counts[gr], 1.0f);
        rowf[cl * 4 + 0] = a0 * inv;
        rowf[cl * 4 + 1] = a1 * inv;
        rowf[cl * 4 + 2] = a2 * inv;
        rowf[cl * 4 + 3] = a3 * inv;
    }
    __syncthreads();
    if (t == 0) {
        float s2 = 0.f;
        for (int k = 0; k < 128; k++) s2 += rowf[k] * Wr[k];
        out[gr] = s2 + br[0];
    } else if (t <= 10) {
        int j = t - 1;
        float s2 = 0.f;
        for (int k = 0; k < 128; k++) s2 += rowf[k] * Wc[k * 10 + j];
        out[G + gr * 10 + j] = s2 + bc[j];
    }
}

// ================================================================ host
extern "C" void kernel_launch(void* const* d_in, const int* in_sizes, int n_in,
                              void* d_out, int out_size, void* d_ws, size_t ws_size,
                              hipStream_t stream) {
    const int*   nt    = (const int*)d_in[0];
    const int*   ih    = (const int*)d_in[1];
    const float* flags = (const float*)d_in[2];
    const int*   depth = (const int*)d_in[3];
    const int*   eidx  = (const int*)d_in[4];
    const int*   batch = (const int*)d_in[5];
    const float* embN  = (const float*)d_in[6];
    const float* embI  = (const float*)d_in[7];
    const float* Ws0   = (const float*)d_in[8];
    const float* bs0   = (const float*)d_in[9];
    const float* Wn0   = (const float*)d_in[10];
    const float* bn0   = (const float*)d_in[11];
    const float* Ws1   = (const float*)d_in[12];
    const float* bs1   = (const float*)d_in[13];
    const float* Wn1   = (const float*)d_in[14];
    const float* bn1   = (const float*)d_in[15];
    const float* Wr    = (const float*)d_in[16];
    const float* br    = (const float*)d_in[17];
    const float* Wc    = (const float*)d_in[18];
    const float* bc    = (const float*)d_in[19];
    float* out = (float*)d_out;

    const int N  = in_sizes[0];
    const int E  = in_sizes[4] / 2;
    const int K0 = in_sizes[8] / HIDDIM;   // 102
    const int G  = out_size / 11;          // 512
    const int* esrc = eidx;
    const int* edst = eidx + E;
    const int NBKT = (N + 255) >> 8;       // 391

    // ---- workspace carve-up
    char* w = (char*)d_ws;
    const size_t NH = (size_t)N * HIDDIM * sizeof(unsigned short);
    unsigned short* bufA  = (unsigned short*)(w);           // x0, later x2
    unsigned short* bufB  = (unsigned short*)(w + NH);      // x1
    unsigned short* bufAX = (unsigned short*)(w + 2 * NH);  // ax (both layers)
    char* p = w + 3 * NH;
    unsigned short* Wt = (unsigned short*)p; p += (size_t)4 * HIDDIM * HIDDIM * 2;  // 128KB
    uint32_t* ebuf = (uint32_t*)p;   p += (size_t)E * 4;
    int* srcs   = (int*)p;           p += (size_t)E * 4;
    int* rowptr = (int*)p;           p += (size_t)(N + 1) * 4;
    float* invd = (float*)p;         p += (size_t)N * 4;
    int* gstart = (int*)p;           p += (size_t)(G + 1) * 4;
    int* boff   = (int*)p;           p += (size_t)(NBKT_MAX + 1) * 4;
    int* bcur   = (int*)p;           p += (size_t)NBKT_MAX * 4;
    // zeroed block: bcount, counts, maxd (contiguous)
    int* bcount = (int*)p;           p += (size_t)NBKT_MAX * 4;
    int* counts = (int*)p;           p += (size_t)G * 4;
    int* maxd   = (int*)p;           p += 4;
    const size_t zero_bytes = (size_t)(NBKT_MAX + G + 1) * 4;
    (void)n_in; (void)ws_size;

    const int nbC = (E + 4095) / 4096;               // 391
    const int nbN = (N + 255) / 256;                 // 391
    const int nbF = ((size_t)N * 16 + 255) / 256;    // 6250 (16 thr/node)
    const int nbG2 = (N + 127) / 128;
    const int nbA = (N + 3) / 4;
    const int nbD = (N + 511) / 512;

    hipMemsetAsync(bcount, 0, zero_bytes, stream);

    // fused prep: feat | bcount | nodestats | wt
    k_prep<<<nbF + nbC + nbN + 256, 256, 0, stream>>>(
        nt, ih, flags, depth, embN, embI, edst, batch,
        Wn0, Ws0, Wn1, Ws1, K0, N, E, G,
        bufA, Wt, bcount, counts, maxd, nbF, nbC, nbN);

    // fused scans + depth column
    k_scan2x<<<2 + nbD, 512, 0, stream>>>(bcount, boff, bcur, rowptr,
                                          counts, gstart, depth, maxd, bufA,
                                          NBKT, N, E, G);

    k_bscatter<<<nbC, 256, 0, stream>>>(esrc, edst, bcur, ebuf, E, NBKT);
    k_build<<<NBKT, 256, 0, stream>>>(ebuf, boff, rowptr, invd, srcs, N);

    const unsigned short* Wt_n0 = Wt;
    const unsigned short* Wt_s0 = Wt + 1 * HIDDIM * HIDDIM;
    const unsigned short* Wt_n1 = Wt + 2 * HIDDIM * HIDDIM;
    const unsigned short* Wt_s1 = Wt + 3 * HIDDIM * HIDDIM;

    // layer 0: ax = invd*(A x0) ; x1 = relu(x0@Ws0 + ax@Wn0 + b)
    k_aggc<<<nbA, 256, 0, stream>>>((const uint4*)bufA, rowptr, srcs, invd,
                                    (uint4*)bufAX, N);
    k_gemm3<<<nbG2, 256, 0, stream>>>(bufA, bufAX, Wt_s0, Wt_n0, N, bs0, bn0, bufB);

    // layer 1: ax = invd*(A x1) ; x2 = relu(x1@Ws1 + ax@Wn1 + b)  (into bufA)
    k_aggc<<<nbA, 256, 0, stream>>>((const uint4*)bufB, rowptr, srcs, invd,
                                    (uint4*)bufAX, N);
    k_gemm3<<<nbG2, 256, 0, stream>>>(bufB, bufAX, Wt_s1, Wt_n1, N, bs1, bn1, bufA);

    // fused pool + heads
    k_poolhead<<<G, 256, 0, stream>>>((const uint32_t*)bufA, gstart, counts,
                                      Wr, br, Wc, bc, out, G);
}